// Round 1
// baseline (32792.856 us; speedup 1.0000x reference)
//
#include <hip/hip_runtime.h>
#include <hip/hip_cooperative_groups.h>
#include <hip/hip_bf16.h>

namespace cg = cooperative_groups;

#define B_   64
#define T_   1024
#define I_   512
#define H_   1024
#define TOP_ 256
#define KTOT 1536          // I_ + H_
#define NWG  128           // persistent workgroups (1 per CU, <=256)
#define NTHR 512           // 8 waves
#define COLS 8             // H_ / NWG h-columns per wg
#define ROWS 32            // 4 gates * COLS weight rows per wg
#define KPAD 1544          // 1536 + 8 bf16 pad -> row stride 3088B (kills bank conflict, keeps 16B align)

typedef __bf16 bf16x8 __attribute__((ext_vector_type(8)));
typedef float  f32x4  __attribute__((ext_vector_type(4)));

struct P {
  const float *x, *h0, *c0, *topic, *Wi, *bi, *Wh, *bh, *Wt, *bt;
  float *out, *hN, *cN;
  __hip_bfloat16 *hb0, *hb1;   // double-buffered h state (bf16) in d_ws
};

__global__ __launch_bounds__(NTHR, 1) void lstm_persist(P p) {
  // weight slice, local row r: gate q = r>>3, col = wg*8 + (r&7); k in [0,1536): k<512 -> Wi, else Wh
  __shared__ __hip_bfloat16 wlds[ROWS][KPAD];
  __shared__ float gl[B_][ROWS + 1];   // gate values, padded

  const int wg   = blockIdx.x;
  const int tid  = threadIdx.x;
  const int lane = tid & 63;
  const int wv   = tid >> 6;    // 0..7
  const int mtile = wv & 3;     // batch tile (16 rows each)
  const int ntile = wv >> 2;    // gate-row tile (16 each)

  // finish-phase ownership: one (batch, col) pair per thread
  const int ob   = tid >> 3;          // 0..63
  const int oc   = tid & 7;           // 0..7
  const int ocol = wg * COLS + oc;    // global h column

  // ---- one-time init ----
  for (int idx = tid; idx < ROWS * KTOT; idx += NTHR) {
    int r = idx / KTOT;
    int k = idx - r * KTOT;
    int R = (r >> 3) * H_ + wg * COLS + (r & 7);   // global gate row
    float w = (k < I_) ? p.Wi[(size_t)R * I_ + k] : p.Wh[(size_t)R * H_ + (k - I_)];
    wlds[r][k] = __float2bfloat16(w);
  }

  float tgv = p.bt[ocol];
  for (int j = 0; j < TOP_; ++j)
    tgv += p.topic[ob * TOP_ + j] * p.Wt[ocol * TOP_ + j];

  const float bias_i = p.bi[ocol]          + p.bh[ocol];
  const float bias_f = p.bi[H_ + ocol]     + p.bh[H_ + ocol];
  const float bias_g = p.bi[2 * H_ + ocol] + p.bh[2 * H_ + ocol];
  const float bias_o = p.bi[3 * H_ + ocol] + p.bh[3 * H_ + ocol];

  float c = p.c0[ob * H_ + ocol];
  p.hb0[ob * H_ + ocol] = __float2bfloat16(p.h0[ob * H_ + ocol]);

  cg::grid_group grid = cg::this_grid();
  grid.sync();

  // MFMA lane geometry (16x16x32 bf16):
  //  A[m][k]: m = lane&15 (within tile), k-block = lane>>4, 8 contiguous k
  //  B[k][n]: n = lane&15, same k-block            (B[k][n] = W[rowlocal=n][k])
  //  D[m][n]: n = lane&15, m = (lane>>4)*4 + reg
  const int arow = mtile * 16 + (lane & 15);   // batch index for A loads
  const int kg8  = (lane >> 4) * 8;            // k sub-offset
  const int brow = ntile * 16 + (lane & 15);   // local gate row (n index)

  for (int t = 0; t < T_; ++t) {
    const __hip_bfloat16* hprev = (t & 1) ? p.hb1 : p.hb0;
    __hip_bfloat16*       hnext = (t & 1) ? p.hb0 : p.hb1;

    f32x4 acc[4];
    #pragma unroll
    for (int u = 0; u < 4; ++u) acc[u] = (f32x4){0.f, 0.f, 0.f, 0.f};

    // x part: k in [0,512), fp32 -> bf16 in regs
    const float* xrow = p.x + ((size_t)arow * T_ + t) * I_ + kg8;
    #pragma unroll
    for (int ks = 0; ks < 16; ++ks) {
      float4 f0 = *(const float4*)(xrow + ks * 32);
      float4 f1 = *(const float4*)(xrow + ks * 32 + 4);
      bf16x8 a;
      a[0] = (__bf16)f0.x; a[1] = (__bf16)f0.y; a[2] = (__bf16)f0.z; a[3] = (__bf16)f0.w;
      a[4] = (__bf16)f1.x; a[5] = (__bf16)f1.y; a[6] = (__bf16)f1.z; a[7] = (__bf16)f1.w;
      bf16x8 b = *(const bf16x8*)&wlds[brow][ks * 32 + kg8];
      acc[ks & 3] = __builtin_amdgcn_mfma_f32_16x16x32_bf16(a, b, acc[ks & 3], 0, 0, 0);
    }

    // h part: k in [512,1536), h already bf16
    const __hip_bfloat16* hrow = hprev + arow * H_ + kg8;
    #pragma unroll
    for (int ks = 0; ks < 32; ++ks) {
      bf16x8 a = *(const bf16x8*)(hrow + ks * 32);
      bf16x8 b = *(const bf16x8*)&wlds[brow][I_ + ks * 32 + kg8];
      acc[ks & 3] = __builtin_amdgcn_mfma_f32_16x16x32_bf16(a, b, acc[ks & 3], 0, 0, 0);
    }

    f32x4 d = acc[0] + acc[1] + acc[2] + acc[3];
    #pragma unroll
    for (int j = 0; j < 4; ++j)
      gl[mtile * 16 + ((lane >> 4) << 2) + j][brow] = d[j];

    __syncthreads();

    // gate finish: one (b, col) per thread
    float gi = gl[ob][oc]      + bias_i + tgv;
    float gf = gl[ob][8 + oc]  + bias_f + tgv;
    float gg = gl[ob][16 + oc] + bias_g;
    float go = gl[ob][24 + oc] + bias_o;

    float ig  = 1.f / (1.f + __expf(-gi));
    float fg  = 1.f / (1.f + __expf(-gf));
    float cg_ = tanhf(gg);
    float og  = 1.f / (1.f + __expf(-go));

    c = fg * c + ig * cg_;
    float h = og * tanhf(c);

    p.out[((size_t)ob * T_ + t) * H_ + ocol] = h;
    hnext[ob * H_ + ocol] = __float2bfloat16(h);
    if (t == T_ - 1) {
      p.hN[ob * H_ + ocol] = h;
      p.cN[ob * H_ + ocol] = c;
    }

    grid.sync();   // publishes h for step t+1; also covers gl/WAR hazards
  }
}

extern "C" void kernel_launch(void* const* d_in, const int* in_sizes, int n_in,
                              void* d_out, int out_size, void* d_ws, size_t ws_size,
                              hipStream_t stream) {
  (void)in_sizes; (void)n_in; (void)out_size; (void)ws_size;

  P p;
  p.x     = (const float*)d_in[0];
  p.h0    = (const float*)d_in[1];
  p.c0    = (const float*)d_in[2];
  p.topic = (const float*)d_in[3];
  p.Wi    = (const float*)d_in[4];
  p.bi    = (const float*)d_in[5];
  p.Wh    = (const float*)d_in[6];
  p.bh    = (const float*)d_in[7];
  p.Wt    = (const float*)d_in[8];
  p.bt    = (const float*)d_in[9];

  float* out = (float*)d_out;
  p.out = out;
  p.hN  = out + (size_t)B_ * T_ * H_;
  p.cN  = p.hN + (size_t)B_ * H_;

  p.hb0 = (__hip_bfloat16*)d_ws;
  p.hb1 = p.hb0 + (size_t)B_ * H_;

  void* args[] = { &p };
  hipLaunchCooperativeKernel((const void*)lstm_persist, dim3(NWG), dim3(NTHR),
                             args, 0, stream);
}

// Round 2
// 27149.014 us; speedup vs baseline: 1.2079x; 1.2079x over previous
//
#include <hip/hip_runtime.h>
#include <hip/hip_bf16.h>
#include <stdint.h>

#define B_   64
#define T_   1024
#define I_   512
#define H_   1024
#define TOP_ 256
#define NWG  128
#define NTHR 512
#define COLS 8            // h columns per workgroup (H_/NWG)
#define ROWS 32           // 4 gates * COLS local gate rows
#define CPW  6            // K-chunks (of 32) per wave; 8 waves * 6 = 48 = 1536/32
#define PLS  (8*ROWS + 8) // pl row stride (floats): 264 -> 2-way read conflicts only

typedef __bf16 bf16x8 __attribute__((ext_vector_type(8)));
typedef float  f32x4  __attribute__((ext_vector_type(4)));

struct P {
  const float *x, *h0, *c0, *topic, *Wi, *bi, *Wh, *bh, *Wt, *bt;
  float *out, *hN, *cN;
  uint32_t *hb0, *hb1;   // h state, packed bf16 pairs, double-buffered (in d_ws)
  uint32_t *bar;         // monotonic grid barrier counter (in d_ws)
};

__device__ __forceinline__ bf16x8 cvt8(float4 f0, float4 f1) {
  bf16x8 v;
  v[0]=(__bf16)f0.x; v[1]=(__bf16)f0.y; v[2]=(__bf16)f0.z; v[3]=(__bf16)f0.w;
  v[4]=(__bf16)f1.x; v[5]=(__bf16)f1.y; v[6]=(__bf16)f1.z; v[7]=(__bf16)f1.w;
  return v;
}

__global__ void lstm_init(P p) {
  int i = blockIdx.x * blockDim.x + threadIdx.x;
  if (i == 0) *p.bar = 0;
  if (i < B_ * H_ / 2) {
    float2 f = ((const float2*)p.h0)[i];
    uint16_t lo = __builtin_bit_cast(uint16_t, (__bf16)f.x);
    uint16_t hi = __builtin_bit_cast(uint16_t, (__bf16)f.y);
    p.hb0[i] = (uint32_t)lo | ((uint32_t)hi << 16);
  }
}

__global__ __launch_bounds__(NTHR, 2) void lstm_persist(P p) {
  __shared__ float pl[B_][PLS];   // per-wave K-partial gates: pl[b][w*32 + r]

  const int wg   = blockIdx.x;
  const int tid  = threadIdx.x;
  const int lane = tid & 63;
  const int w    = tid >> 6;            // wave 0..7 (K-split owner)
  const int l15  = lane & 15;
  const int kg8  = (lane >> 4) << 3;    // MFMA k sub-offset (0,8,16,24)

  // ---- weights resident in VGPRs (48 VGPRs), B-fragment layout ----
  bf16x8 wreg[CPW][2];
  #pragma unroll
  for (int i = 0; i < CPW; ++i) {
    const int kc = w * CPW + i;
    const int k0 = kc * 32 + kg8;
    #pragma unroll
    for (int n = 0; n < 2; ++n) {
      const int row = n * 16 + l15;                       // local gate row 0..31
      const int R   = (row >> 3) * H_ + wg * COLS + (row & 7);  // global gate row
      const float* src = (k0 < I_) ? (p.Wi + (size_t)R * I_ + k0)
                                   : (p.Wh + (size_t)R * H_ + (k0 - I_));
      wreg[i][n] = cvt8(*(const float4*)src, *(const float4*)(src + 4));
    }
  }

  // ---- finish-phase ownership: one (batch, col) per thread ----
  const int ob = tid >> 3, oc = tid & 7, ocol = wg * COLS + oc;
  float tgv = p.bt[ocol];
  for (int j = 0; j < TOP_; ++j)
    tgv += p.topic[ob * TOP_ + j] * p.Wt[(size_t)ocol * TOP_ + j];
  const float bias_i = p.bi[ocol]        + p.bh[ocol]        + tgv;
  const float bias_f = p.bi[H_ + ocol]   + p.bh[H_ + ocol]   + tgv;
  const float bias_g = p.bi[2*H_ + ocol] + p.bh[2*H_ + ocol];
  const float bias_o = p.bi[3*H_ + ocol] + p.bh[3*H_ + ocol];
  float c = p.c0[ob * H_ + ocol];

  for (int t = 0; t < T_; ++t) {
    const uint32_t* hp = (t & 1) ? p.hb1 : p.hb0;
    uint32_t*       hn = (t & 1) ? p.hb0 : p.hb1;

    f32x4 acc[4][2];
    #pragma unroll
    for (int m = 0; m < 4; ++m) { acc[m][0] = (f32x4){0,0,0,0}; acc[m][1] = (f32x4){0,0,0,0}; }

    #pragma unroll
    for (int i = 0; i < CPW; ++i) {
      const int kc = w * CPW + i;
      bf16x8 a[4];
      if (kc < 16) {                      // x part (k < 512), fp32 -> bf16, L2-cached plain loads
        const int k0 = kc * 32 + kg8;
        #pragma unroll
        for (int m = 0; m < 4; ++m) {
          const float* xr = p.x + ((size_t)(m*16 + l15) * T_ + t) * I_ + k0;
          a[m] = cvt8(*(const float4*)xr, *(const float4*)(xr + 4));
        }
      } else {                            // h part: agent-scope (LLC-coherent) loads
        const int kh = kc * 32 - I_ + kg8;
        #pragma unroll
        for (int m = 0; m < 4; ++m) {
          const uint32_t* hr = hp + (((m*16 + l15) * H_ + kh) >> 1);
          union { bf16x8 v; uint32_t u[4]; } z;
          #pragma unroll
          for (int j = 0; j < 4; ++j)
            z.u[j] = __hip_atomic_load(hr + j, __ATOMIC_RELAXED, __HIP_MEMORY_SCOPE_AGENT);
          a[m] = z.v;
        }
      }
      #pragma unroll
      for (int m = 0; m < 4; ++m) {
        acc[m][0] = __builtin_amdgcn_mfma_f32_16x16x32_bf16(a[m], wreg[i][0], acc[m][0], 0, 0, 0);
        acc[m][1] = __builtin_amdgcn_mfma_f32_16x16x32_bf16(a[m], wreg[i][1], acc[m][1], 0, 0, 0);
      }
    }

    // partial gates -> LDS  (C/D layout: col = lane&15, row = (lane>>4)*4 + j)
    #pragma unroll
    for (int m = 0; m < 4; ++m)
      #pragma unroll
      for (int n = 0; n < 2; ++n)
        #pragma unroll
        for (int j = 0; j < 4; ++j)
          pl[m*16 + (lane >> 4)*4 + j][w*32 + n*16 + l15] = acc[m][n][j];

    __syncthreads();

    // reduce 8 K-partials and finish gates
    float g0 = 0.f, g1 = 0.f, g2 = 0.f, g3 = 0.f;
    #pragma unroll
    for (int ww = 0; ww < 8; ++ww) {
      g0 += pl[ob][ww*32 +      oc];
      g1 += pl[ob][ww*32 +  8 + oc];
      g2 += pl[ob][ww*32 + 16 + oc];
      g3 += pl[ob][ww*32 + 24 + oc];
    }

    float ig = 1.f / (1.f + __expf(-(g0 + bias_i)));
    float fg = 1.f / (1.f + __expf(-(g1 + bias_f)));
    float cg = tanhf(g2 + bias_g);
    float og = 1.f / (1.f + __expf(-(g3 + bias_o)));
    c = fg * c + ig * cg;
    float hy = og * tanhf(c);

    p.out[((size_t)ob * T_ + t) * H_ + ocol] = hy;

    // publish h (packed bf16 pair) via agent-scope store -> LLC
    uint32_t mine  = (uint32_t)__builtin_bit_cast(uint16_t, (__bf16)hy);
    uint32_t other = (uint32_t)__shfl_xor((int)mine, 1);
    if (!(tid & 1))
      __hip_atomic_store(hn + ((ob * H_ + ocol) >> 1), mine | (other << 16),
                         __ATOMIC_RELAXED, __HIP_MEMORY_SCOPE_AGENT);

    if (t == T_ - 1) { p.hN[ob*H_ + ocol] = hy; p.cN[ob*H_ + ocol] = c; }

    // ---- lightweight grid barrier: no cache flushes ----
    __syncthreads();   // compiler drains vmcnt(0) before s_barrier -> h stores at LLC
    if (tid == 0) {
      __hip_atomic_fetch_add(p.bar, 1u, __ATOMIC_RELEASE, __HIP_MEMORY_SCOPE_AGENT);
      const uint32_t tgt = (uint32_t)(t + 1) * NWG;
      while (__hip_atomic_load(p.bar, __ATOMIC_RELAXED, __HIP_MEMORY_SCOPE_AGENT) < tgt) {}
    }
    __syncthreads();
  }
}

extern "C" void kernel_launch(void* const* d_in, const int* in_sizes, int n_in,
                              void* d_out, int out_size, void* d_ws, size_t ws_size,
                              hipStream_t stream) {
  (void)in_sizes; (void)n_in; (void)out_size; (void)ws_size;

  P p;
  p.x     = (const float*)d_in[0];
  p.h0    = (const float*)d_in[1];
  p.c0    = (const float*)d_in[2];
  p.topic = (const float*)d_in[3];
  p.Wi    = (const float*)d_in[4];
  p.bi    = (const float*)d_in[5];
  p.Wh    = (const float*)d_in[6];
  p.bh    = (const float*)d_in[7];
  p.Wt    = (const float*)d_in[8];
  p.bt    = (const float*)d_in[9];

  float* out = (float*)d_out;
  p.out = out;
  p.hN  = out + (size_t)B_ * T_ * H_;
  p.cN  = p.hN + (size_t)B_ * H_;

  p.hb0 = (uint32_t*)d_ws;                       // 131072 B
  p.hb1 = p.hb0 + (B_ * H_ / 2);                 // 131072 B
  p.bar = (uint32_t*)((char*)d_ws + 2 * 131072 + 256);

  lstm_init<<<dim3((B_ * H_ / 2 + 255) / 256), dim3(256), 0, stream>>>(p);
  lstm_persist<<<dim3(NWG), dim3(NTHR), 0, stream>>>(p);
}

// Round 3
// 12129.030 us; speedup vs baseline: 2.7037x; 2.2384x over previous
//
#include <hip/hip_runtime.h>
#include <hip/hip_bf16.h>
#include <stdint.h>

#define B_   64
#define T_   1024
#define I_   512
#define H_   1024
#define TOP_ 256
#define NWG  128
#define NTHR 512
#define PLS  260       // pl row stride (floats): 64*260*4 = 66560 B, ~2-way banks

typedef __bf16 bf16x8 __attribute__((ext_vector_type(8)));
typedef float  f32x4  __attribute__((ext_vector_type(4)));

struct P {
  const float *x, *h0, *c0, *topic, *Wi, *bi, *Wh, *bh, *Wt, *bt;
  float *out, *hN, *cN;
  uint32_t *hb0, *hb1;   // h state, packed bf16, double-buffered (d_ws)
  uint32_t *bar;         // 8 barrier counters, 256 B apart (d_ws)
};

__device__ __forceinline__ bf16x8 cvt8(float4 f0, float4 f1) {
  bf16x8 v;
  v[0]=(__bf16)f0.x; v[1]=(__bf16)f0.y; v[2]=(__bf16)f0.z; v[3]=(__bf16)f0.w;
  v[4]=(__bf16)f1.x; v[5]=(__bf16)f1.y; v[6]=(__bf16)f1.z; v[7]=(__bf16)f1.w;
  return v;
}

__device__ __forceinline__ uint2 pack4(float4 f) {
  uint2 u;
  u.x = (uint32_t)__builtin_bit_cast(uint16_t, (__bf16)f.x)
      | ((uint32_t)__builtin_bit_cast(uint16_t, (__bf16)f.y) << 16);
  u.y = (uint32_t)__builtin_bit_cast(uint16_t, (__bf16)f.z)
      | ((uint32_t)__builtin_bit_cast(uint16_t, (__bf16)f.w) << 16);
  return u;
}

__global__ void lstm_init(P p) {
  int i = blockIdx.x * blockDim.x + threadIdx.x;
  if (i < 8) p.bar[i * 64] = 0;
  if (i < B_ * H_ / 2) {
    float2 f = ((const float2*)p.h0)[i];
    uint16_t lo = __builtin_bit_cast(uint16_t, (__bf16)f.x);
    uint16_t hi = __builtin_bit_cast(uint16_t, (__bf16)f.y);
    p.hb0[i] = (uint32_t)lo | ((uint32_t)hi << 16);
  }
}

__global__ __launch_bounds__(NTHR, 2) void lstm_persist(P p) {
  // x staged in MFMA A-fragment layout: [kc][m][lane][8 bf16] -> conflict-free ds_read_b128
  __shared__ ushort xs[16][4][64][8];      // 65536 B
  __shared__ float  pl[B_][PLS];           // 66560 B

  const int wg   = blockIdx.x;
  const int tid  = threadIdx.x;
  const int lane = tid & 63;
  const int w    = tid >> 6;          // wave 0..7
  const int l15  = lane & 15;
  const int hi   = lane >> 4;         // 0..3
  const int kg8  = hi * 8;

  // ---- weights resident in VGPRs: wave w owns x-chunks {2w,2w+1}, h-chunks {4w..4w+3} ----
  bf16x8 wx[2][2], wh[4][2];
  #pragma unroll
  for (int n = 0; n < 2; ++n) {
    const int row = n * 16 + l15;                              // local gate row 0..31
    const int R   = (row >> 3) * H_ + wg * 8 + (row & 7);      // global gate row
    #pragma unroll
    for (int i = 0; i < 2; ++i) {
      const float* s = p.Wi + (size_t)R * I_ + (2 * w + i) * 32 + kg8;
      wx[i][n] = cvt8(*(const float4*)s, *(const float4*)(s + 4));
    }
    #pragma unroll
    for (int i = 0; i < 4; ++i) {
      const float* s = p.Wh + (size_t)R * H_ + (4 * w + i) * 32 + kg8;
      wh[i][n] = cvt8(*(const float4*)s, *(const float4*)(s + 4));
    }
  }

  // ---- finish-phase ownership: one (batch, col) per thread ----
  const int ob = tid >> 3, oc = tid & 7, ocol = wg * 8 + oc;
  float tgv = p.bt[ocol];
  for (int j = 0; j < TOP_ / 4; ++j) {
    float4 tv = ((const float4*)(p.topic + (size_t)ob * TOP_))[j];
    float4 wv = ((const float4*)(p.Wt + (size_t)ocol * TOP_))[j];
    tgv += tv.x * wv.x + tv.y * wv.y + tv.z * wv.z + tv.w * wv.w;
  }
  const float bias_i = p.bi[ocol]        + p.bh[ocol]        + tgv;
  const float bias_f = p.bi[H_ + ocol]   + p.bh[H_ + ocol]   + tgv;
  const float bias_g = p.bi[2*H_ + ocol] + p.bh[2*H_ + ocol];
  const float bias_o = p.bi[3*H_ + ocol] + p.bh[3*H_ + ocol];
  float c = p.c0[ob * H_ + ocol];

  // staging identity: thread (sb, sr) covers x[sb][t][4*(8j+sr) .. +3], j=0..15
  const int sb = tid >> 3, sr = tid & 7;
  const int s_m   = sb >> 4;
  const int s_lf  = (sr >> 1) * 16 + (sb & 15);
  const int s_off = (sr & 1) * 4;

  // ---- prologue: stage x(0) ----
  #pragma unroll
  for (int j = 0; j < 16; ++j) {
    float4 f = *(const float4*)(p.x + (size_t)sb * T_ * I_ + 4 * (8 * j + sr));
    *(uint2*)&xs[j][s_m][s_lf][s_off] = pack4(f);
  }
  __syncthreads();

  for (int t = 0; t < T_; ++t) {
    const __hip_bfloat16* hp = (const __hip_bfloat16*)((t & 1) ? p.hb1 : p.hb0);
    uint32_t*             hn = (t & 1) ? p.hb0 : p.hb1;

    // A: issue ALL h loads up front (agent-scope 8B atomics -> LLC, one latency round)
    bf16x8 hv[4][4];
    #pragma unroll
    for (int i = 0; i < 4; ++i) {
      const int kh = (4 * w + i) * 32 + kg8;
      #pragma unroll
      for (int m = 0; m < 4; ++m) {
        const unsigned long long* q =
            (const unsigned long long*)(hp + (size_t)(m * 16 + l15) * H_ + kh);
        union { bf16x8 v; unsigned long long u[2]; } z;
        z.u[0] = __hip_atomic_load(q,     __ATOMIC_RELAXED, __HIP_MEMORY_SCOPE_AGENT);
        z.u[1] = __hip_atomic_load(q + 1, __ATOMIC_RELAXED, __HIP_MEMORY_SCOPE_AGENT);
        hv[i][m] = z.v;
      }
    }

    // B: x MFMAs from LDS (available immediately; overlaps h-load latency)
    f32x4 acc[4][2];
    #pragma unroll
    for (int m = 0; m < 4; ++m) { acc[m][0] = (f32x4){0,0,0,0}; acc[m][1] = (f32x4){0,0,0,0}; }
    #pragma unroll
    for (int i = 0; i < 2; ++i) {
      const int kc = 2 * w + i;
      #pragma unroll
      for (int m = 0; m < 4; ++m) {
        bf16x8 a = *(const bf16x8*)&xs[kc][m][lane][0];
        acc[m][0] = __builtin_amdgcn_mfma_f32_16x16x32_bf16(a, wx[i][0], acc[m][0], 0, 0, 0);
        acc[m][1] = __builtin_amdgcn_mfma_f32_16x16x32_bf16(a, wx[i][1], acc[m][1], 0, 0, 0);
      }
    }

    // C: h MFMAs (compiler inserts the vmcnt wait for hv)
    #pragma unroll
    for (int i = 0; i < 4; ++i)
      #pragma unroll
      for (int m = 0; m < 4; ++m) {
        acc[m][0] = __builtin_amdgcn_mfma_f32_16x16x32_bf16(hv[i][m], wh[i][0], acc[m][0], 0, 0, 0);
        acc[m][1] = __builtin_amdgcn_mfma_f32_16x16x32_bf16(hv[i][m], wh[i][1], acc[m][1], 0, 0, 0);
      }

    // D: partial gates -> LDS (C/D layout: col = lane&15, row = hi*4 + j)
    #pragma unroll
    for (int m = 0; m < 4; ++m)
      #pragma unroll
      for (int n = 0; n < 2; ++n)
        #pragma unroll
        for (int j = 0; j < 4; ++j)
          pl[m * 16 + hi * 4 + j][w * 32 + n * 16 + l15] = acc[m][n][j];
    __syncthreads();

    // F1: issue x(t+1) stage loads (fly under the gate-finish + barrier window)
    float4 xf[16];
    if (t + 1 < T_) {
      #pragma unroll
      for (int j = 0; j < 16; ++j)
        xf[j] = *(const float4*)(p.x + ((size_t)sb * T_ + (t + 1)) * I_ + 4 * (8 * j + sr));
    }

    // E: reduce 8 K-partials, finish gates
    float g0 = 0.f, g1 = 0.f, g2 = 0.f, g3 = 0.f;
    #pragma unroll
    for (int ww = 0; ww < 8; ++ww) {
      g0 += pl[ob][ww * 32 +      oc];
      g1 += pl[ob][ww * 32 +  8 + oc];
      g2 += pl[ob][ww * 32 + 16 + oc];
      g3 += pl[ob][ww * 32 + 24 + oc];
    }
    float ig = 1.f / (1.f + __expf(-(g0 + bias_i)));
    float fg = 1.f / (1.f + __expf(-(g1 + bias_f)));
    float cg = tanhf(g2 + bias_g);
    float og = 1.f / (1.f + __expf(-(g3 + bias_o)));
    c = fg * c + ig * cg;
    float hy = og * tanhf(c);

    // out: non-temporal (no L2/L3 allocate) -> stops evicting x from L3
    __builtin_nontemporal_store(hy, &p.out[((size_t)ob * T_ + t) * H_ + ocol]);

    // publish h (packed bf16 pair) via agent-scope store -> LLC
    uint32_t mine  = (uint32_t)__builtin_bit_cast(uint16_t, (__bf16)hy);
    uint32_t other = (uint32_t)__shfl_xor((int)mine, 1);
    if (!(tid & 1))
      __hip_atomic_store(hn + ((ob * H_ + ocol) >> 1), mine | (other << 16),
                         __ATOMIC_RELAXED, __HIP_MEMORY_SCOPE_AGENT);

    if (t == T_ - 1) { p.hN[ob * H_ + ocol] = hy; p.cN[ob * H_ + ocol] = c; }

    // F2: write staged x(t+1) into xs (everyone finished reading x(t) at D-sync)
    if (t + 1 < T_) {
      #pragma unroll
      for (int j = 0; j < 16; ++j)
        *(uint2*)&xs[j][s_m][s_lf][s_off] = pack4(xf[j]);
    }

    // G: tree grid-barrier (relaxed; h went via LLC-bypass stores, drained by syncthreads)
    __syncthreads();
    if (tid < 8) {
      if (tid == 0)
        __hip_atomic_fetch_add(p.bar + (wg & 7) * 64, 1u,
                               __ATOMIC_RELAXED, __HIP_MEMORY_SCOPE_AGENT);
      const uint32_t tgt = (uint32_t)(t + 1) * (NWG / 8);
      while (__hip_atomic_load(p.bar + tid * 64,
                               __ATOMIC_RELAXED, __HIP_MEMORY_SCOPE_AGENT) < tgt)
        __builtin_amdgcn_s_sleep(1);
    }
    __syncthreads();
  }
}

extern "C" void kernel_launch(void* const* d_in, const int* in_sizes, int n_in,
                              void* d_out, int out_size, void* d_ws, size_t ws_size,
                              hipStream_t stream) {
  (void)in_sizes; (void)n_in; (void)out_size; (void)ws_size;

  P p;
  p.x     = (const float*)d_in[0];
  p.h0    = (const float*)d_in[1];
  p.c0    = (const float*)d_in[2];
  p.topic = (const float*)d_in[3];
  p.Wi    = (const float*)d_in[4];
  p.bi    = (const float*)d_in[5];
  p.Wh    = (const float*)d_in[6];
  p.bh    = (const float*)d_in[7];
  p.Wt    = (const float*)d_in[8];
  p.bt    = (const float*)d_in[9];

  float* out = (float*)d_out;
  p.out = out;
  p.hN  = out + (size_t)B_ * T_ * H_;
  p.cN  = p.hN + (size_t)B_ * H_;

  p.hb0 = (uint32_t*)d_ws;                        // 131072 B
  p.hb1 = p.hb0 + (B_ * H_ / 2);                  // 131072 B
  p.bar = (uint32_t*)((char*)d_ws + 2 * 131072);  // 8 counters, 256 B apart

  lstm_init<<<dim3(128), dim3(256), 0, stream>>>(p);
  lstm_persist<<<dim3(NWG), dim3(NTHR), 0, stream>>>(p);
}